// Round 8
// baseline (632.422 us; speedup 1.0000x reference)
//
#include <hip/hip_runtime.h>

// RNNT joint: out = log_softmax( tanh(enc@W_e + dec@W_d + b1) @ W2 )
// B=4, T=256, U=128, D=512, NCLS=1024.
// Single fused joint kernel, m97-style: hidden lives entirely in LDS (no HBM
// intermediate); W2 staged per-K-step into double-buffered LDS via
// global_load_lds (bulk async DMA = real MLP, unlike per-wave L2 prefetch
// which capped at ~36 GB/s/CU across rounds 1-7).
// Block: 16 waves, 64 rows x 1024 cols; wave-tile 64x64 (acc 64 VGPR).
// ws layout: ep 2MB | dp 1MB | w2p 1MB  (4MB total)

#define BB 4
#define TT 256
#define UU 128
#define DD 512
#define CC 1024

using f32x16 = __attribute__((ext_vector_type(16))) float;
using f32x4  = __attribute__((ext_vector_type(4))) float;
using bf16x8 = __attribute__((ext_vector_type(8))) __bf16;

static __device__ __forceinline__ unsigned short f2bf(float f) {
    unsigned int u = __float_as_uint(f);
    unsigned int r = (u + 0x7FFFu + ((u >> 16) & 1u)) >> 16;
    return (unsigned short)r;
}

static __device__ __forceinline__ float tanh_fast(float x) {
    float a = x * 2.8853900817779268f;           // 2*log2(e)
    a = fminf(30.f, fmaxf(-30.f, a));
    float e = __expf(a * 0.6931471805599453f);
    float r = __builtin_amdgcn_rcpf(e + 1.0f);
    return __builtin_fmaf(-2.f, r, 1.f);
}

// bulk async global->LDS copy, 16B per lane
static __device__ __forceinline__ void gl2lds16(const void* g, void* l) {
    __builtin_amdgcn_global_load_lds(
        (const __attribute__((address_space(1))) void*)g,
        (__attribute__((address_space(3))) void*)l, 16, 0, 0);
}

// ---- prep: fused enc/dec projection ----
__global__ __launch_bounds__(256) void proj_fused(
    const float* __restrict__ enc, const float* __restrict__ dec,
    const float* __restrict__ W_e, const float* __restrict__ W_d,
    const float* __restrict__ b1,
    float* __restrict__ ep, float* __restrict__ dp)
{
    __shared__ float As[32][34];
    __shared__ float Ws[32][68];
    const int mb = blockIdx.x * 32;
    const int n0 = blockIdx.y * 64;
    const bool is_enc = (mb < BB * TT);
    const float* A = is_enc ? enc + (size_t)mb * DD
                            : dec + (size_t)(mb - BB * TT) * DD;
    const float* W = is_enc ? W_e : W_d;
    float* C = is_enc ? ep + (size_t)mb * DD
                      : dp + (size_t)(mb - BB * TT) * DD;
    const int tid = threadIdx.x;
    const int tx = tid & 15, ty = tid >> 4;
    float acc[2][4] = {};
    for (int k0 = 0; k0 < DD; k0 += 32) {
        __syncthreads();
        {
            const int row = tid >> 3, kk = (tid & 7) * 4;
            float4 v = *reinterpret_cast<const float4*>(A + (size_t)row * DD + k0 + kk);
            As[kk][row] = v.x; As[kk + 1][row] = v.y;
            As[kk + 2][row] = v.z; As[kk + 3][row] = v.w;
            const int wk = tid >> 3, wc2 = (tid & 7) * 8;
            float4 w0 = *reinterpret_cast<const float4*>(W + (size_t)(k0 + wk) * DD + n0 + wc2);
            float4 w1 = *reinterpret_cast<const float4*>(W + (size_t)(k0 + wk) * DD + n0 + wc2 + 4);
            *reinterpret_cast<float4*>(&Ws[wk][wc2]) = w0;
            *reinterpret_cast<float4*>(&Ws[wk][wc2 + 4]) = w1;
        }
        __syncthreads();
        #pragma unroll 4
        for (int kk = 0; kk < 32; ++kk) {
            float a0 = As[kk][ty * 2], a1 = As[kk][ty * 2 + 1];
            float w0 = Ws[kk][tx * 4], w1 = Ws[kk][tx * 4 + 1];
            float w2 = Ws[kk][tx * 4 + 2], w3 = Ws[kk][tx * 4 + 3];
            acc[0][0] += a0 * w0; acc[0][1] += a0 * w1;
            acc[0][2] += a0 * w2; acc[0][3] += a0 * w3;
            acc[1][0] += a1 * w0; acc[1][1] += a1 * w1;
            acc[1][2] += a1 * w2; acc[1][3] += a1 * w3;
        }
    }
    float bb[4] = {0.f, 0.f, 0.f, 0.f};
    if (is_enc) {
        #pragma unroll
        for (int j = 0; j < 4; ++j) bb[j] = b1[n0 + tx * 4 + j];
    }
    #pragma unroll
    for (int i = 0; i < 2; ++i) {
        float4 v;
        v.x = acc[i][0] + bb[0]; v.y = acc[i][1] + bb[1];
        v.z = acc[i][2] + bb[2]; v.w = acc[i][3] + bb[3];
        *reinterpret_cast<float4*>(C + (size_t)(ty * 2 + i) * DD + n0 + tx * 4) = v;
    }
}

// ---- prep: pack W2 -> bf16 fragment-major: 16B frag (ktag,c) at unit ktag*1024+c ----
// K-step kb's slab (ktags 2kb,2kb+1) is the contiguous 32KB at byte kb*32768.
__global__ __launch_bounds__(256) void pack_w2(
    const float* __restrict__ W2, unsigned short* __restrict__ w2p)
{
    int i = blockIdx.x * 256 + threadIdx.x;
    int k = i >> 10, c = i & 1023;
    int idx = (((k >> 3) * CC) + c) * 8 + (k & 7);
    w2p[idx] = f2bf(W2[i]);
}

// ---- fused joint: hidden in LDS, W2 double-buffered via global_load_lds ----
// grid = 2048 (64 rows each: bt = r>>1, u0 = (r&1)*64), block = 1024 = 16 waves.
// Wave-tile 64 rows x 64 cols (wave w covers cols w*64..w*64+63).
// Swapped MFMA: acc = mfma(W2frag, hidfrag) -> D lane = u-row, lane-local stats.
__global__ __launch_bounds__(1024, 4) void joint_lds(
    const float* __restrict__ ep, const float* __restrict__ dp,
    const unsigned short* __restrict__ w2p, float* __restrict__ out)
{
    __shared__ __align__(16) unsigned char hidL[64 * 1024];   // hidden frags, later store slots
    __shared__ __align__(16) unsigned char wbA[32768];        // W2 K-step dbuf
    __shared__ __align__(16) unsigned char wbB[32768];
    __shared__ float maxb[64][17];
    __shared__ float sumb[64][17];

    const int r   = blockIdx.x;
    const int bt  = r >> 1;
    const int u0  = (r & 1) * 64;
    const int b   = bt >> 8;
    const int tid = threadIdx.x;

    const unsigned char* w2g = (const unsigned char*)w2p;

    // ---- prologue: hidden = tanh(ep+dp) -> LDS frags; stage W2 slab 0 ----
    {
        const int row = tid >> 4;                 // 0..63
        const int kq  = tid & 15;
        const float* eprow = ep + (size_t)bt * DD;
        const float* dprow = dp + (size_t)(b * UU + u0 + row) * DD;
        #pragma unroll
        for (int c = 0; c < 4; ++c) {
            const int ktag = kq + c * 16;
            const int k0 = ktag * 8;
            float4 e0 = *reinterpret_cast<const float4*>(eprow + k0);
            float4 e1 = *reinterpret_cast<const float4*>(eprow + k0 + 4);
            float4 d0 = *reinterpret_cast<const float4*>(dprow + k0);
            float4 d1 = *reinterpret_cast<const float4*>(dprow + k0 + 4);
            float h0 = tanh_fast(e0.x + d0.x), h1 = tanh_fast(e0.y + d0.y);
            float h2 = tanh_fast(e0.z + d0.z), h3 = tanh_fast(e0.w + d0.w);
            float h4 = tanh_fast(e1.x + d1.x), h5 = tanh_fast(e1.y + d1.y);
            float h6 = tanh_fast(e1.z + d1.z), h7 = tanh_fast(e1.w + d1.w);
            uint4 pk;
            pk.x = (unsigned)f2bf(h0) | ((unsigned)f2bf(h1) << 16);
            pk.y = (unsigned)f2bf(h2) | ((unsigned)f2bf(h3) << 16);
            pk.z = (unsigned)f2bf(h4) | ((unsigned)f2bf(h5) << 16);
            pk.w = (unsigned)f2bf(h6) | ((unsigned)f2bf(h7) << 16);
            const int rsw = ((row ^ ktag) & 31) | (row & 32);
            *reinterpret_cast<uint4*>(hidL + ktag * 1024 + rsw * 16) = pk;
        }
        gl2lds16(w2g + tid * 16,         wbA + tid * 16);
        gl2lds16(w2g + 16384 + tid * 16, wbA + 16384 + tid * 16);
    }
    __syncthreads();   // drains gl_lds (vmcnt) + hidden ds_writes

    const int lane = tid & 63;
    const int w    = tid >> 6;            // 0..15 : 64-col slice
    const int g    = lane >> 5;           // k-half
    const int l31  = lane & 31;           // u-row within row-group

    unsigned char* curb = wbA;
    unsigned char* nxtb = wbB;

    f32x16 acc00 = {}, acc01 = {}, acc10 = {}, acc11 = {};

    #define MFMA __builtin_amdgcn_mfma_f32_32x32x16_bf16
    for (int kb = 0; kb < 32; ++kb) {
        if (kb < 31) {
            const unsigned char* src = w2g + (size_t)(kb + 1) * 32768;
            gl2lds16(src + tid * 16,         nxtb + tid * 16);
            gl2lds16(src + 16384 + tid * 16, nxtb + 16384 + tid * 16);
        }
        const int ktag = 2 * kb + g;
        const int rs = ((l31 ^ ktag) & 31) << 4;
        bf16x8 h0 = *reinterpret_cast<const bf16x8*>(hidL + ktag * 1024 + rs);
        bf16x8 h1 = *reinterpret_cast<const bf16x8*>(hidL + ktag * 1024 + 512 + rs);
        bf16x8 a0 = *reinterpret_cast<const bf16x8*>(curb + ((g * 1024 + w * 64 + l31) << 4));
        bf16x8 a1 = *reinterpret_cast<const bf16x8*>(curb + ((g * 1024 + w * 64 + 32 + l31) << 4));
        acc00 = MFMA(a0, h0, acc00, 0, 0, 0);
        acc01 = MFMA(a0, h1, acc01, 0, 0, 0);
        acc10 = MFMA(a1, h0, acc10, 0, 0, 0);
        acc11 = MFMA(a1, h1, acc11, 0, 0, 0);
        __syncthreads();   // vmcnt(0): stage done; all waves done reading curb
        unsigned char* t = curb; curb = nxtb; nxtb = t;
    }
    #undef MFMA

    // ---- lane-local row stats: lane's 32 logits of row l31 in acc00/acc10 (g-split),
    // row 32+l31 in acc01/acc11. Merge g via shfl32, waves via LDS. ----
    float m0 = -3.0e38f, m1 = -3.0e38f;
    #pragma unroll
    for (int q = 0; q < 16; ++q) {
        m0 = fmaxf(m0, fmaxf(acc00[q], acc10[q]));
        m1 = fmaxf(m1, fmaxf(acc01[q], acc11[q]));
    }
    m0 = fmaxf(m0, __shfl_xor(m0, 32, 64));
    m1 = fmaxf(m1, __shfl_xor(m1, 32, 64));
    if (lane < 32) { maxb[l31][w] = m0; maxb[32 + l31][w] = m1; }
    __syncthreads();
    float rmax0 = maxb[l31][0], rmax1 = maxb[32 + l31][0];
    #pragma unroll
    for (int j = 1; j < 16; ++j) {
        rmax0 = fmaxf(rmax0, maxb[l31][j]);
        rmax1 = fmaxf(rmax1, maxb[32 + l31][j]);
    }
    float s0 = 0.f, s1 = 0.f;
    #pragma unroll
    for (int q = 0; q < 16; ++q) {
        s0 += __expf(acc00[q] - rmax0) + __expf(acc10[q] - rmax0);
        s1 += __expf(acc01[q] - rmax1) + __expf(acc11[q] - rmax1);
    }
    s0 += __shfl_xor(s0, 32, 64);
    s1 += __shfl_xor(s1, 32, 64);
    if (lane < 32) { sumb[l31][w] = s0; sumb[32 + l31][w] = s1; }
    __syncthreads();
    float t0 = 0.f, t1 = 0.f;
    #pragma unroll
    for (int j = 0; j < 16; ++j) { t0 += sumb[l31][j]; t1 += sumb[32 + l31][j]; }
    const float lse0 = rmax0 + __logf(t0);   // row l31
    const float lse1 = rmax1 + __logf(t1);   // row 32+l31

    // ---- per-wave LDS transpose (32x32 f32 tiles) + coalesced nontemporal stores ----
    unsigned char* slot = hidL + w * 4096;   // hidden region now dead
    const int rr = lane >> 1, seg = lane & 1;
    const float lse_r0 = __shfl(lse0, rr, 64);
    const float lse_r1 = __shfl(lse1, rr, 64);
    float* outbase = out + (size_t)r * 64 * CC + w * 64;

    #define CHUNK(MR, T, ACC, LSER) { \
        _Pragma("unroll") \
        for (int j = 0; j < 4; ++j) { \
            f32x4 v; \
            v.x = ACC[4 * j]; v.y = ACC[4 * j + 1]; \
            v.z = ACC[4 * j + 2]; v.w = ACC[4 * j + 3]; \
            *reinterpret_cast<f32x4*>(slot + l31 * 128 + (((2 * j + g) ^ (l31 & 7)) << 4)) = v; \
        } \
        asm volatile("s_waitcnt lgkmcnt(0)" ::: "memory"); \
        f32x4 q0 = *reinterpret_cast<const f32x4*>(slot + rr * 128 + (((seg * 4 + 0) ^ (rr & 7)) << 4)); \
        f32x4 q1 = *reinterpret_cast<const f32x4*>(slot + rr * 128 + (((seg * 4 + 1) ^ (rr & 7)) << 4)); \
        f32x4 q2 = *reinterpret_cast<const f32x4*>(slot + rr * 128 + (((seg * 4 + 2) ^ (rr & 7)) << 4)); \
        f32x4 q3 = *reinterpret_cast<const f32x4*>(slot + rr * 128 + (((seg * 4 + 3) ^ (rr & 7)) << 4)); \
        float* op = outbase + (size_t)((MR) * 32 + rr) * CC + (T) * 32 + seg * 16; \
        q0 -= LSER; q1 -= LSER; q2 -= LSER; q3 -= LSER; \
        __builtin_nontemporal_store(q0, reinterpret_cast<f32x4*>(op + 0)); \
        __builtin_nontemporal_store(q1, reinterpret_cast<f32x4*>(op + 4)); \
        __builtin_nontemporal_store(q2, reinterpret_cast<f32x4*>(op + 8)); \
        __builtin_nontemporal_store(q3, reinterpret_cast<f32x4*>(op + 12)); \
        asm volatile("s_waitcnt lgkmcnt(0)" ::: "memory"); \
    }
    CHUNK(0, 0, acc00, lse_r0)
    CHUNK(0, 1, acc10, lse_r0)
    CHUNK(1, 0, acc01, lse_r1)
    CHUNK(1, 1, acc11, lse_r1)
    #undef CHUNK
}

extern "C" void kernel_launch(void* const* d_in, const int* in_sizes, int n_in,
                              void* d_out, int out_size, void* d_ws, size_t ws_size,
                              hipStream_t stream) {
    const float* enc = (const float*)d_in[0];
    const float* dec = (const float*)d_in[1];
    const float* W_e = (const float*)d_in[2];
    const float* W_d = (const float*)d_in[3];
    const float* b1  = (const float*)d_in[4];
    const float* W2  = (const float*)d_in[5];
    float* out = (float*)d_out;

    char* ws = (char*)d_ws;
    float* ep = (float*)(ws);                                  // 2MB
    float* dp = (float*)(ws + (2u << 20));                     // 1MB
    unsigned short* w2p = (unsigned short*)(ws + (3u << 20));  // 1MB

    hipLaunchKernelGGL(pack_w2, dim3((DD * CC) / 256), dim3(256), 0, stream, W2, w2p);
    hipLaunchKernelGGL(proj_fused, dim3((BB * TT + BB * UU) / 32, DD / 64), dim3(256), 0,
                       stream, enc, dec, W_e, W_d, b1, ep, dp);
    hipLaunchKernelGGL(joint_lds, dim3(BB * TT * UU / 64), dim3(1024), 0, stream,
                       ep, dp, w2p, out);
}

// Round 9
// 466.086 us; speedup vs baseline: 1.3569x; 1.3569x over previous
//
#include <hip/hip_runtime.h>

// RNNT joint: out = log_softmax( tanh(enc@W_e + dec@W_d + b1) @ W2 )
// B=4, T=256, U=128, D=512, NCLS=1024.
// Split design: K1 writes packed bf16 hidden (128MB) to ws (L3-resident);
// K2 = barrier-free register GEMM + fused log-softmax.
// K2: 8 waves/block, 32 rows x 1024 cols, wave tile 32x128, depth-1 staging.
// ROUND 9 CHANGE (only one): output stores are PLAIN (through-L2), not
// nontemporal. Rounds 6-8 showed nt stores cause ~400MB partial-line write
// amplification and cap effective write BW at ~1.5-1.8 TB/s; the L2
// write-back path (round 5 spill evidence) sustains 2.6+ TB/s.
// ws layout: ep 2MB | dp 1MB | w2p 1MB | hidp 128MB  (total 132MB)

#define BB 4
#define TT 256
#define UU 128
#define DD 512
#define CC 1024

using f32x16 = __attribute__((ext_vector_type(16))) float;
using f32x4  = __attribute__((ext_vector_type(4))) float;
using bf16x8 = __attribute__((ext_vector_type(8))) __bf16;
using u32x4  = __attribute__((ext_vector_type(4))) unsigned int;

static __device__ __forceinline__ unsigned short f2bf(float f) {
    unsigned int u = __float_as_uint(f);
    unsigned int r = (u + 0x7FFFu + ((u >> 16) & 1u)) >> 16;
    return (unsigned short)r;
}

static __device__ __forceinline__ float tanh_fast(float x) {
    float a = x * 2.8853900817779268f;           // 2*log2(e)
    a = fminf(30.f, fmaxf(-30.f, a));
    float e = __expf(a * 0.6931471805599453f);
    float r = __builtin_amdgcn_rcpf(e + 1.0f);
    return __builtin_fmaf(-2.f, r, 1.f);
}

// ---- prep: fused enc/dec projection ----
__global__ __launch_bounds__(256) void proj_fused(
    const float* __restrict__ enc, const float* __restrict__ dec,
    const float* __restrict__ W_e, const float* __restrict__ W_d,
    const float* __restrict__ b1,
    float* __restrict__ ep, float* __restrict__ dp)
{
    __shared__ float As[32][34];
    __shared__ float Ws[32][68];
    const int mb = blockIdx.x * 32;
    const int n0 = blockIdx.y * 64;
    const bool is_enc = (mb < BB * TT);
    const float* A = is_enc ? enc + (size_t)mb * DD
                            : dec + (size_t)(mb - BB * TT) * DD;
    const float* W = is_enc ? W_e : W_d;
    float* C = is_enc ? ep + (size_t)mb * DD
                      : dp + (size_t)(mb - BB * TT) * DD;
    const int tid = threadIdx.x;
    const int tx = tid & 15, ty = tid >> 4;
    float acc[2][4] = {};
    for (int k0 = 0; k0 < DD; k0 += 32) {
        __syncthreads();
        {
            const int row = tid >> 3, kk = (tid & 7) * 4;
            float4 v = *reinterpret_cast<const float4*>(A + (size_t)row * DD + k0 + kk);
            As[kk][row] = v.x; As[kk + 1][row] = v.y;
            As[kk + 2][row] = v.z; As[kk + 3][row] = v.w;
            const int wk = tid >> 3, wc2 = (tid & 7) * 8;
            float4 w0 = *reinterpret_cast<const float4*>(W + (size_t)(k0 + wk) * DD + n0 + wc2);
            float4 w1 = *reinterpret_cast<const float4*>(W + (size_t)(k0 + wk) * DD + n0 + wc2 + 4);
            *reinterpret_cast<float4*>(&Ws[wk][wc2]) = w0;
            *reinterpret_cast<float4*>(&Ws[wk][wc2 + 4]) = w1;
        }
        __syncthreads();
        #pragma unroll 4
        for (int kk = 0; kk < 32; ++kk) {
            float a0 = As[kk][ty * 2], a1 = As[kk][ty * 2 + 1];
            float w0 = Ws[kk][tx * 4], w1 = Ws[kk][tx * 4 + 1];
            float w2 = Ws[kk][tx * 4 + 2], w3 = Ws[kk][tx * 4 + 3];
            acc[0][0] += a0 * w0; acc[0][1] += a0 * w1;
            acc[0][2] += a0 * w2; acc[0][3] += a0 * w3;
            acc[1][0] += a1 * w0; acc[1][1] += a1 * w1;
            acc[1][2] += a1 * w2; acc[1][3] += a1 * w3;
        }
    }
    float bb[4] = {0.f, 0.f, 0.f, 0.f};
    if (is_enc) {
        #pragma unroll
        for (int j = 0; j < 4; ++j) bb[j] = b1[n0 + tx * 4 + j];
    }
    #pragma unroll
    for (int i = 0; i < 2; ++i) {
        float4 v;
        v.x = acc[i][0] + bb[0]; v.y = acc[i][1] + bb[1];
        v.z = acc[i][2] + bb[2]; v.w = acc[i][3] + bb[3];
        *reinterpret_cast<float4*>(C + (size_t)(ty * 2 + i) * DD + n0 + tx * 4) = v;
    }
}

// ---- prep: pack W2 -> bf16 fragment layout: 16B frag (ktag,c) at unit ktag*1024+c ----
__global__ __launch_bounds__(256) void pack_w2(
    const float* __restrict__ W2, unsigned short* __restrict__ w2p)
{
    int i = blockIdx.x * 256 + threadIdx.x;
    int k = i >> 10, c = i & 1023;
    int idx = (((k >> 3) * CC) + c) * 8 + (k & 7);
    w2p[idx] = f2bf(W2[i]);
}

// ---- K1: hidden = tanh(ep + dp) -> packed bf16 fragments in global ----
// 16B frag (R, ktag, l): unit index R*2048 + ktag*32 + l, R = row>>5, l = row&31,
// row = bt*128 + u. Plain stores so the 128MB lands in L2/L3 for K2.
__global__ __launch_bounds__(256) void hidden_gen(
    const float* __restrict__ ep, const float* __restrict__ dp,
    u32x4* __restrict__ hidp)
{
    const int idx = blockIdx.x * 256 + threadIdx.x;   // 0 .. 4096*2048-1
    const int l = idx & 31;
    const int ktag = (idx >> 5) & 63;
    const int R = idx >> 11;
    const int h = R * 32 + l;          // global row
    const int bt = h >> 7;             // b*T + t
    const int u  = h & 127;
    const int b  = bt >> 8;
    const float* e = ep + (size_t)bt * DD + ktag * 8;
    const float* d = dp + (size_t)(b * UU + u) * DD + ktag * 8;
    float4 e0 = *reinterpret_cast<const float4*>(e);
    float4 e1 = *reinterpret_cast<const float4*>(e + 4);
    float4 d0 = *reinterpret_cast<const float4*>(d);
    float4 d1 = *reinterpret_cast<const float4*>(d + 4);
    float h0 = tanh_fast(e0.x + d0.x), h1 = tanh_fast(e0.y + d0.y);
    float h2 = tanh_fast(e0.z + d0.z), h3 = tanh_fast(e0.w + d0.w);
    float h4 = tanh_fast(e1.x + d1.x), h5 = tanh_fast(e1.y + d1.y);
    float h6 = tanh_fast(e1.z + d1.z), h7 = tanh_fast(e1.w + d1.w);
    u32x4 pk;
    pk.x = (unsigned)f2bf(h0) | ((unsigned)f2bf(h1) << 16);
    pk.y = (unsigned)f2bf(h2) | ((unsigned)f2bf(h3) << 16);
    pk.z = (unsigned)f2bf(h4) | ((unsigned)f2bf(h5) << 16);
    pk.w = (unsigned)f2bf(h6) | ((unsigned)f2bf(h7) << 16);
    hidp[idx] = pk;
}

// ---- K2: barrier-free register GEMM + log-softmax ----
// grid = 4096 blocks (32 rows each), block = 512 thr = 8 waves x 128 cols.
// Wave tile 32 rows x 128 cols, swapped orientation (acc = mfma(W2frag, hidfrag)):
// D col = u-row -> lane-local stats. Depth-1 double-buffer staging via
// compile-time-indexed stage arrays (full unroll -> constant folds).
__global__ __launch_bounds__(512, 4) void gemm_lsm(
    const u32x4* __restrict__ hidp, const unsigned short* __restrict__ w2p,
    float* __restrict__ out)
{
    __shared__ __align__(16) unsigned char slots[8 * 4096];
    __shared__ float maxw[32][9];
    __shared__ float sumw[32][9];

    const int r   = blockIdx.x;          // 32-row tile, 0..4095
    const int tid = threadIdx.x;
    const int w    = tid >> 6;           // 0..7 : 128-col slice
    const int lane = tid & 63;
    const int g    = lane >> 5;          // k-half
    const int l31  = lane & 31;          // = u-row within tile

    const u32x4* hb = hidp + (size_t)r * 2048 + g * 32 + l31;
    const u32x4* wb = reinterpret_cast<const u32x4*>(w2p)
                    + (size_t)g * 1024 + w * 128 + l31;

    #define LDH(kk) (*reinterpret_cast<const bf16x8*>(hb + (kk) * 64))
    #define LDW(kk, t) (*reinterpret_cast<const bf16x8*>(wb + (size_t)(kk) * 2048 + (t) * 32))
    #define MFMA __builtin_amdgcn_mfma_f32_32x32x16_bf16

    f32x16 a0 = {}, a1 = {}, a2 = {}, a3 = {};

    bf16x8 hstage[2];
    bf16x8 wstage[2][4];

    hstage[0] = LDH(0);
    wstage[0][0] = LDW(0, 0); wstage[0][1] = LDW(0, 1);
    wstage[0][2] = LDW(0, 2); wstage[0][3] = LDW(0, 3);

    #pragma unroll
    for (int kk = 0; kk < 32; ++kk) {
        const int cur = kk & 1, nxt = cur ^ 1;
        if (kk < 31) {
            hstage[nxt] = LDH(kk + 1);
            wstage[nxt][0] = LDW(kk + 1, 0);
            wstage[nxt][1] = LDW(kk + 1, 1);
            wstage[nxt][2] = LDW(kk + 1, 2);
            wstage[nxt][3] = LDW(kk + 1, 3);
        }
        a0 = MFMA(wstage[cur][0], hstage[cur], a0, 0, 0, 0);
        a1 = MFMA(wstage[cur][1], hstage[cur], a1, 0, 0, 0);
        a2 = MFMA(wstage[cur][2], hstage[cur], a2, 0, 0, 0);
        a3 = MFMA(wstage[cur][3], hstage[cur], a3, 0, 0, 0);
    }
    #undef LDH
    #undef LDW
    #undef MFMA

    // ---- lane-local row stats: lane holds all 64 block-local logits of row l31
    // (cols w*128 + t*32 + (q&3)+8*(q>>2)+4*g). Merge g-halves, then waves via LDS.
    float m = -3.0e38f;
    #pragma unroll
    for (int q = 0; q < 16; ++q)
        m = fmaxf(m, fmaxf(fmaxf(a0[q], a1[q]), fmaxf(a2[q], a3[q])));
    m = fmaxf(m, __shfl_xor(m, 32, 64));
    if (lane < 32) maxw[l31][w] = m;
    __syncthreads();
    float rmax = maxw[l31][0];
    #pragma unroll
    for (int j = 1; j < 8; ++j) rmax = fmaxf(rmax, maxw[l31][j]);
    float s = 0.f;
    #pragma unroll
    for (int q = 0; q < 16; ++q)
        s += __expf(a0[q] - rmax) + __expf(a1[q] - rmax)
           + __expf(a2[q] - rmax) + __expf(a3[q] - rmax);
    s += __shfl_xor(s, 32, 64);
    if (lane < 32) sumw[l31][w] = s;
    __syncthreads();
    float tot = 0.f;
    #pragma unroll
    for (int j = 0; j < 8; ++j) tot += sumw[l31][j];
    const float lse = rmax + __logf(tot);          // lse for row l31

    // ---- per-wave LDS transpose (32x32 f32 tiles), then PLAIN coalesced
    // stores (through L2; L2 merges the 16B pieces into full lines) ----
    unsigned char* slot = slots + w * 4096;
    const int rr = lane >> 1, seg = lane & 1;
    const float lse_r = __shfl(lse, rr, 64);       // lse for row rr
    float* outbase = out + (size_t)r * 32 * CC + w * 128;

    #define CHUNK(T, ACC) { \
        _Pragma("unroll") \
        for (int j = 0; j < 4; ++j) { \
            f32x4 v; \
            v.x = ACC[4 * j]; v.y = ACC[4 * j + 1]; \
            v.z = ACC[4 * j + 2]; v.w = ACC[4 * j + 3]; \
            *reinterpret_cast<f32x4*>(slot + l31 * 128 + (((2 * j + g) ^ (l31 & 7)) << 4)) = v; \
        } \
        asm volatile("s_waitcnt lgkmcnt(0)" ::: "memory"); \
        f32x4 q0 = *reinterpret_cast<const f32x4*>(slot + rr * 128 + (((seg * 4 + 0) ^ (rr & 7)) << 4)); \
        f32x4 q1 = *reinterpret_cast<const f32x4*>(slot + rr * 128 + (((seg * 4 + 1) ^ (rr & 7)) << 4)); \
        f32x4 q2 = *reinterpret_cast<const f32x4*>(slot + rr * 128 + (((seg * 4 + 2) ^ (rr & 7)) << 4)); \
        f32x4 q3 = *reinterpret_cast<const f32x4*>(slot + rr * 128 + (((seg * 4 + 3) ^ (rr & 7)) << 4)); \
        float* op = outbase + (size_t)rr * CC + (T) * 32 + seg * 16; \
        q0 -= lse_r; q1 -= lse_r; q2 -= lse_r; q3 -= lse_r; \
        *reinterpret_cast<f32x4*>(op + 0)  = q0; \
        *reinterpret_cast<f32x4*>(op + 4)  = q1; \
        *reinterpret_cast<f32x4*>(op + 8)  = q2; \
        *reinterpret_cast<f32x4*>(op + 12) = q3; \
        asm volatile("s_waitcnt lgkmcnt(0)" ::: "memory"); \
    }
    CHUNK(0, a0)
    CHUNK(1, a1)
    CHUNK(2, a2)
    CHUNK(3, a3)
    #undef CHUNK
}

// ---- fallback fused joint (round-2 kernel) for small ws ----
__global__ __launch_bounds__(1024) void joint_fused(
    const float* __restrict__ ep, const float* __restrict__ dp,
    const unsigned short* __restrict__ w2p, float* __restrict__ out)
{
    __shared__ __align__(16) unsigned char ldsA[64 * 1024];
    __shared__ float maxbuf[64][17];
    __shared__ float sumbuf[64][17];
    __shared__ float rowmax_s[64];
    __shared__ float rowlse[64];

    const int bid = blockIdx.x;
    const int bt  = bid >> 1;
    const int u0  = (bid & 1) * 64;
    const int b   = bt >> 8;
    const int tid = threadIdx.x;
    {
        const int row = tid >> 4;
        const int kq  = tid & 15;
        const float* eprow = ep + (size_t)bt * DD;
        const float* dprow = dp + (size_t)(b * UU + u0 + row) * DD;
        #pragma unroll
        for (int c = 0; c < 4; ++c) {
            const int ktag = kq + c * 16;
            const int k0 = ktag * 8;
            float4 e0 = *reinterpret_cast<const float4*>(eprow + k0);
            float4 e1 = *reinterpret_cast<const float4*>(eprow + k0 + 4);
            float4 d0 = *reinterpret_cast<const float4*>(dprow + k0);
            float4 d1 = *reinterpret_cast<const float4*>(dprow + k0 + 4);
            float h0 = tanh_fast(e0.x + d0.x), h1 = tanh_fast(e0.y + d0.y);
            float h2 = tanh_fast(e0.z + d0.z), h3 = tanh_fast(e0.w + d0.w);
            float h4 = tanh_fast(e1.x + d1.x), h5 = tanh_fast(e1.y + d1.y);
            float h6 = tanh_fast(e1.z + d1.z), h7 = tanh_fast(e1.w + d1.w);
            uint4 pk;
            pk.x = (unsigned)f2bf(h0) | ((unsigned)f2bf(h1) << 16);
            pk.y = (unsigned)f2bf(h2) | ((unsigned)f2bf(h3) << 16);
            pk.z = (unsigned)f2bf(h4) | ((unsigned)f2bf(h5) << 16);
            pk.w = (unsigned)f2bf(h6) | ((unsigned)f2bf(h7) << 16);
            *reinterpret_cast<uint4*>(ldsA + ktag * 1024 + ((row ^ (ktag & 7)) << 4)) = pk;
        }
    }
    __syncthreads();

    const int lane = tid & 63;
    const int w    = tid >> 6;
    const int g    = lane >> 5;
    const int l31  = lane & 31;
    const int col0 = w * 64;

    const unsigned short* wb0 = w2p + (size_t)(col0 + l31) * 8;
    const unsigned short* wb1 = w2p + (size_t)(col0 + 32 + l31) * 8;

    f32x16 acc00 = {}, acc01 = {}, acc10 = {}, acc11 = {};
    bf16x8 bf0 = *reinterpret_cast<const bf16x8*>(wb0 + (size_t)g * (CC * 8));
    bf16x8 bf1 = *reinterpret_cast<const bf16x8*>(wb1 + (size_t)g * (CC * 8));

    #pragma unroll 2
    for (int kk = 0; kk < 32; ++kk) {
        const int ktag = kk * 2 + g;
        const unsigned char* ab = ldsA + ktag * 1024 + ((l31 ^ (ktag & 7)) << 4);
        bf16x8 fa0 = *reinterpret_cast<const bf16x8*>(ab);
        bf16x8 fa1 = *reinterpret_cast<const bf16x8*>(ab + 512);
        const int ktn = ((kk + 1) & 31) * 2 + g;
        bf16x8 nb0 = *reinterpret_cast<const bf16x8*>(wb0 + (size_t)ktn * (CC * 8));
        bf16x8 nb1 = *reinterpret_cast<const bf16x8*>(wb1 + (size_t)ktn * (CC * 8));
        acc00 = __builtin_amdgcn_mfma_f32_32x32x16_bf16(fa0, bf0, acc00, 0, 0, 0);
        acc10 = __builtin_amdgcn_mfma_f32_32x32x16_bf16(fa1, bf0, acc10, 0, 0, 0);
        acc01 = __builtin_amdgcn_mfma_f32_32x32x16_bf16(fa0, bf1, acc01, 0, 0, 0);
        acc11 = __builtin_amdgcn_mfma_f32_32x32x16_bf16(fa1, bf1, acc11, 0, 0, 0);
        bf0 = nb0; bf1 = nb1;
    }

    #pragma unroll
    for (int i = 0; i < 2; ++i) {
        float pr[16];
        #pragma unroll
        for (int q = 0; q < 16; ++q)
            pr[q] = (i == 0) ? fmaxf(acc00[q], acc01[q]) : fmaxf(acc10[q], acc11[q]);
        #pragma unroll
        for (int off = 16; off >= 1; off >>= 1)
            #pragma unroll
            for (int q = 0; q < 16; ++q)
                pr[q] = fmaxf(pr[q], __shfl_xor(pr[q], off, 64));
        if (l31 == 0)
            #pragma unroll
            for (int q = 0; q < 16; ++q)
                maxbuf[i * 32 + (q & 3) + 8 * (q >> 2) + 4 * g][w] = pr[q];
    }
    __syncthreads();
    if (tid < 64) {
        float mm = maxbuf[tid][0];
        #pragma unroll
        for (int j = 1; j < 16; ++j) mm = fmaxf(mm, maxbuf[tid][j]);
        rowmax_s[tid] = mm;
    }
    __syncthreads();
    #pragma unroll
    for (int i = 0; i < 2; ++i) {
        float ps[16];
        #pragma unroll
        for (int q = 0; q < 16; ++q) {
            const int r32 = i * 32 + (q & 3) + 8 * (q >> 2) + 4 * g;
            const float rm = rowmax_s[r32];
            ps[q] = (i == 0) ? __expf(acc00[q] - rm) + __expf(acc01[q] - rm)
                             : __expf(acc10[q] - rm) + __expf(acc11[q] - rm);
        }
        #pragma unroll
        for (int off = 16; off >= 1; off >>= 1)
            #pragma unroll
            for (int q = 0; q < 16; ++q)
                ps[q] += __shfl_xor(ps[q], off, 64);
        if (l31 == 0)
            #pragma unroll
            for (int q = 0; q < 16; ++q)
                sumbuf[i * 32 + (q & 3) + 8 * (q >> 2) + 4 * g][w] = ps[q];
    }
    __syncthreads();
    if (tid < 64) {
        float ss = 0.f;
        #pragma unroll
        for (int j = 0; j < 16; ++j) ss += sumbuf[tid][j];
        rowlse[tid] = rowmax_s[tid] + __logf(ss);
    }
    __syncthreads();

    float* outp = out + ((size_t)(bt * UU + u0)) * CC + col0 + l31;
    #pragma unroll
    for (int q = 0; q < 16; ++q) {
        const int r32 = (q & 3) + 8 * (q >> 2) + 4 * g;
        const float l0 = rowlse[r32];
        const float l1 = rowlse[32 + r32];
        outp[(size_t)r32 * CC]              = acc00[q] - l0;
        outp[(size_t)r32 * CC + 32]         = acc01[q] - l0;
        outp[(size_t)(32 + r32) * CC]       = acc10[q] - l1;
        outp[(size_t)(32 + r32) * CC + 32]  = acc11[q] - l1;
    }
}

extern "C" void kernel_launch(void* const* d_in, const int* in_sizes, int n_in,
                              void* d_out, int out_size, void* d_ws, size_t ws_size,
                              hipStream_t stream) {
    const float* enc = (const float*)d_in[0];
    const float* dec = (const float*)d_in[1];
    const float* W_e = (const float*)d_in[2];
    const float* W_d = (const float*)d_in[3];
    const float* b1  = (const float*)d_in[4];
    const float* W2  = (const float*)d_in[5];
    float* out = (float*)d_out;

    char* ws = (char*)d_ws;
    float* ep = (float*)(ws);                                  // 2MB
    float* dp = (float*)(ws + (2u << 20));                     // 1MB
    unsigned short* w2p = (unsigned short*)(ws + (3u << 20));  // 1MB
    u32x4* hidp = (u32x4*)(ws + (4u << 20));                   // 128MB

    hipLaunchKernelGGL(pack_w2, dim3((DD * CC) / 256), dim3(256), 0, stream, W2, w2p);
    hipLaunchKernelGGL(proj_fused, dim3((BB * TT + BB * UU) / 32, DD / 64), dim3(256), 0,
                       stream, enc, dec, W_e, W_d, b1, ep, dp);

    const size_t need = (size_t)(4u << 20) + (size_t)128 * 1024 * 1024;
    if (ws_size >= need) {
        hipLaunchKernelGGL(hidden_gen, dim3((BB * TT * UU * 64) / 256), dim3(256), 0,
                           stream, ep, dp, hidp);
        hipLaunchKernelGGL(gemm_lsm, dim3(BB * TT * UU / 32), dim3(512), 0, stream,
                           hidp, w2p, out);
    } else {
        hipLaunchKernelGGL(joint_fused, dim3(BB * TT * 2), dim3(1024), 0, stream,
                           ep, dp, w2p, out);
    }
}

// Round 10
// 379.559 us; speedup vs baseline: 1.6662x; 1.2280x over previous
//
#include <hip/hip_runtime.h>

// RNNT joint: out = log_softmax( tanh(enc@W_e + dec@W_d + b1) @ W2 )
// B=4, T=256, U=128, D=512, NCLS=1024.
// Split design: K1 writes packed bf16 hidden (128MB) to ws; K2 = barrier-light
// register GEMM + fused log-softmax.
// ROUND 10 THEORY: R9's 410us = W2 4.3GB served at ~10.5 TB/s (L3 rate) because
// the kernel's own streaming traffic (512MB stores + 128MB hidden reads) evicts
// the 1MB W2 from each XCD L2. Fix: hidden loads nontemporal, output stores
// nontemporal BUT fully lane-contiguous (block-wide LDS transpose -> each store
// instruction covers 1KB contiguous, so no partial-line amplification).
// ws layout: ep 2MB | dp 1MB | w2p 1MB | hidp 128MB  (total 132MB)

#define BB 4
#define TT 256
#define UU 128
#define DD 512
#define CC 1024
#define ESTRIDE 1044   // 16-row transpose buffer stride (floats): 16B-aligned rows, <=2-way banks

using f32x16 = __attribute__((ext_vector_type(16))) float;
using f32x4  = __attribute__((ext_vector_type(4))) float;
using bf16x8 = __attribute__((ext_vector_type(8))) __bf16;
using u32x4  = __attribute__((ext_vector_type(4))) unsigned int;

static __device__ __forceinline__ unsigned short f2bf(float f) {
    unsigned int u = __float_as_uint(f);
    unsigned int r = (u + 0x7FFFu + ((u >> 16) & 1u)) >> 16;
    return (unsigned short)r;
}

static __device__ __forceinline__ float tanh_fast(float x) {
    float a = x * 2.8853900817779268f;           // 2*log2(e)
    a = fminf(30.f, fmaxf(-30.f, a));
    float e = __expf(a * 0.6931471805599453f);
    float r = __builtin_amdgcn_rcpf(e + 1.0f);
    return __builtin_fmaf(-2.f, r, 1.f);
}

// ---- prep: fused enc/dec projection ----
__global__ __launch_bounds__(256) void proj_fused(
    const float* __restrict__ enc, const float* __restrict__ dec,
    const float* __restrict__ W_e, const float* __restrict__ W_d,
    const float* __restrict__ b1,
    float* __restrict__ ep, float* __restrict__ dp)
{
    __shared__ float As[32][34];
    __shared__ float Ws[32][68];
    const int mb = blockIdx.x * 32;
    const int n0 = blockIdx.y * 64;
    const bool is_enc = (mb < BB * TT);
    const float* A = is_enc ? enc + (size_t)mb * DD
                            : dec + (size_t)(mb - BB * TT) * DD;
    const float* W = is_enc ? W_e : W_d;
    float* C = is_enc ? ep + (size_t)mb * DD
                      : dp + (size_t)(mb - BB * TT) * DD;
    const int tid = threadIdx.x;
    const int tx = tid & 15, ty = tid >> 4;
    float acc[2][4] = {};
    for (int k0 = 0; k0 < DD; k0 += 32) {
        __syncthreads();
        {
            const int row = tid >> 3, kk = (tid & 7) * 4;
            float4 v = *reinterpret_cast<const float4*>(A + (size_t)row * DD + k0 + kk);
            As[kk][row] = v.x; As[kk + 1][row] = v.y;
            As[kk + 2][row] = v.z; As[kk + 3][row] = v.w;
            const int wk = tid >> 3, wc2 = (tid & 7) * 8;
            float4 w0 = *reinterpret_cast<const float4*>(W + (size_t)(k0 + wk) * DD + n0 + wc2);
            float4 w1 = *reinterpret_cast<const float4*>(W + (size_t)(k0 + wk) * DD + n0 + wc2 + 4);
            *reinterpret_cast<float4*>(&Ws[wk][wc2]) = w0;
            *reinterpret_cast<float4*>(&Ws[wk][wc2 + 4]) = w1;
        }
        __syncthreads();
        #pragma unroll 4
        for (int kk = 0; kk < 32; ++kk) {
            float a0 = As[kk][ty * 2], a1 = As[kk][ty * 2 + 1];
            float w0 = Ws[kk][tx * 4], w1 = Ws[kk][tx * 4 + 1];
            float w2 = Ws[kk][tx * 4 + 2], w3 = Ws[kk][tx * 4 + 3];
            acc[0][0] += a0 * w0; acc[0][1] += a0 * w1;
            acc[0][2] += a0 * w2; acc[0][3] += a0 * w3;
            acc[1][0] += a1 * w0; acc[1][1] += a1 * w1;
            acc[1][2] += a1 * w2; acc[1][3] += a1 * w3;
        }
    }
    float bb[4] = {0.f, 0.f, 0.f, 0.f};
    if (is_enc) {
        #pragma unroll
        for (int j = 0; j < 4; ++j) bb[j] = b1[n0 + tx * 4 + j];
    }
    #pragma unroll
    for (int i = 0; i < 2; ++i) {
        float4 v;
        v.x = acc[i][0] + bb[0]; v.y = acc[i][1] + bb[1];
        v.z = acc[i][2] + bb[2]; v.w = acc[i][3] + bb[3];
        *reinterpret_cast<float4*>(C + (size_t)(ty * 2 + i) * DD + n0 + tx * 4) = v;
    }
}

// ---- prep: pack W2 -> bf16 fragment layout: 16B frag (ktag,c) at unit ktag*1024+c ----
__global__ __launch_bounds__(256) void pack_w2(
    const float* __restrict__ W2, unsigned short* __restrict__ w2p)
{
    int i = blockIdx.x * 256 + threadIdx.x;
    int k = i >> 10, c = i & 1023;
    int idx = (((k >> 3) * CC) + c) * 8 + (k & 7);
    w2p[idx] = f2bf(W2[i]);
}

// ---- K1: hidden = tanh(ep + dp) -> packed bf16 fragments in global ----
__global__ __launch_bounds__(256) void hidden_gen(
    const float* __restrict__ ep, const float* __restrict__ dp,
    u32x4* __restrict__ hidp)
{
    const int idx = blockIdx.x * 256 + threadIdx.x;   // 0 .. 4096*2048-1
    const int l = idx & 31;
    const int ktag = (idx >> 5) & 63;
    const int R = idx >> 11;
    const int h = R * 32 + l;          // global row
    const int bt = h >> 7;             // b*T + t
    const int u  = h & 127;
    const int b  = bt >> 8;
    const float* e = ep + (size_t)bt * DD + ktag * 8;
    const float* d = dp + (size_t)(b * UU + u) * DD + ktag * 8;
    float4 e0 = *reinterpret_cast<const float4*>(e);
    float4 e1 = *reinterpret_cast<const float4*>(e + 4);
    float4 d0 = *reinterpret_cast<const float4*>(d);
    float4 d1 = *reinterpret_cast<const float4*>(d + 4);
    float h0 = tanh_fast(e0.x + d0.x), h1 = tanh_fast(e0.y + d0.y);
    float h2 = tanh_fast(e0.z + d0.z), h3 = tanh_fast(e0.w + d0.w);
    float h4 = tanh_fast(e1.x + d1.x), h5 = tanh_fast(e1.y + d1.y);
    float h6 = tanh_fast(e1.z + d1.z), h7 = tanh_fast(e1.w + d1.w);
    u32x4 pk;
    pk.x = (unsigned)f2bf(h0) | ((unsigned)f2bf(h1) << 16);
    pk.y = (unsigned)f2bf(h2) | ((unsigned)f2bf(h3) << 16);
    pk.z = (unsigned)f2bf(h4) | ((unsigned)f2bf(h5) << 16);
    pk.w = (unsigned)f2bf(h6) | ((unsigned)f2bf(h7) << 16);
    hidp[idx] = pk;
}

// ---- K2: register GEMM + log-softmax ----
// grid = 4096 blocks (32 rows each), block = 512 thr = 8 waves x 128 cols.
// Wave tile 32 rows x 128 cols, swapped orientation: D col = u-row -> lane-local
// stats. Hidden loads nontemporal (read-once, keep L2 clean for W2).
// Epilogue: block-wide LDS transpose (16 rows x 1024 f32, stride 1044) then
// fully lane-contiguous nontemporal f32x4 stores (1KB per instruction).
__global__ __launch_bounds__(512, 4) void gemm_lsm(
    const u32x4* __restrict__ hidp, const unsigned short* __restrict__ w2p,
    float* __restrict__ out)
{
    __shared__ __align__(16) float ebuf[16 * ESTRIDE];   // ~66.8KB transpose buffer
    __shared__ float maxw[32][9];
    __shared__ float sumw[32][9];

    const int r   = blockIdx.x;          // 32-row tile, 0..4095
    const int tid = threadIdx.x;
    const int w    = tid >> 6;           // 0..7 : 128-col slice
    const int lane = tid & 63;
    const int g    = lane >> 5;          // k-half
    const int l31  = lane & 31;          // = u-row within tile

    const u32x4* hb = hidp + (size_t)r * 2048 + g * 32 + l31;
    const u32x4* wb = reinterpret_cast<const u32x4*>(w2p)
                    + (size_t)g * 1024 + w * 128 + l31;

    #define LDH(kk) (__builtin_nontemporal_load(reinterpret_cast<const bf16x8*>(hb + (kk) * 64)))
    #define LDW(kk, t) (*reinterpret_cast<const bf16x8*>(wb + (size_t)(kk) * 2048 + (t) * 32))
    #define MFMA __builtin_amdgcn_mfma_f32_32x32x16_bf16

    f32x16 a0 = {}, a1 = {}, a2 = {}, a3 = {};

    bf16x8 hstage[2];
    bf16x8 wstage[2][4];

    hstage[0] = LDH(0);
    wstage[0][0] = LDW(0, 0); wstage[0][1] = LDW(0, 1);
    wstage[0][2] = LDW(0, 2); wstage[0][3] = LDW(0, 3);

    #pragma unroll
    for (int kk = 0; kk < 32; ++kk) {
        const int cur = kk & 1, nxt = cur ^ 1;
        if (kk < 31) {
            hstage[nxt] = LDH(kk + 1);
            wstage[nxt][0] = LDW(kk + 1, 0);
            wstage[nxt][1] = LDW(kk + 1, 1);
            wstage[nxt][2] = LDW(kk + 1, 2);
            wstage[nxt][3] = LDW(kk + 1, 3);
        }
        a0 = MFMA(wstage[cur][0], hstage[cur], a0, 0, 0, 0);
        a1 = MFMA(wstage[cur][1], hstage[cur], a1, 0, 0, 0);
        a2 = MFMA(wstage[cur][2], hstage[cur], a2, 0, 0, 0);
        a3 = MFMA(wstage[cur][3], hstage[cur], a3, 0, 0, 0);
    }
    #undef LDH
    #undef LDW
    #undef MFMA

    // ---- lane-local row stats: lane holds all 64 block-local logits of row l31
    // (cols w*128 + t*32 + (q&3)+8*(q>>2)+4*g). Merge g-halves, then waves via LDS.
    float m = -3.0e38f;
    #pragma unroll
    for (int q = 0; q < 16; ++q)
        m = fmaxf(m, fmaxf(fmaxf(a0[q], a1[q]), fmaxf(a2[q], a3[q])));
    m = fmaxf(m, __shfl_xor(m, 32, 64));
    if (lane < 32) maxw[l31][w] = m;
    __syncthreads();
    float rmax = maxw[l31][0];
    #pragma unroll
    for (int j = 1; j < 8; ++j) rmax = fmaxf(rmax, maxw[l31][j]);
    float s = 0.f;
    #pragma unroll
    for (int q = 0; q < 16; ++q)
        s += __expf(a0[q] - rmax) + __expf(a1[q] - rmax)
           + __expf(a2[q] - rmax) + __expf(a3[q] - rmax);
    s += __shfl_xor(s, 32, 64);
    if (lane < 32) sumw[l31][w] = s;
    __syncthreads();
    float tot = 0.f;
    #pragma unroll
    for (int j = 0; j < 8; ++j) tot += sumw[l31][j];
    const float lse = rmax + __logf(tot);          // lse for row l31 (lane-local)

    // ---- epilogue: two 16-row halves. Scatter (acc - lse) into ebuf[row][col],
    // then stream out with lane-contiguous nontemporal f32x4 stores. ----
    #pragma unroll
    for (int h2 = 0; h2 < 2; ++h2) {
        if ((l31 >> 4) == h2) {
            const int rl = l31 & 15;
            float* erow = ebuf + rl * ESTRIDE;
            const int cb = w * 128 + 4 * g;
            #pragma unroll
            for (int q = 0; q < 16; ++q) {
                const int cq = cb + (q & 3) + 8 * (q >> 2);
                erow[cq]      = a0[q] - lse;
                erow[cq + 32] = a1[q] - lse;
                erow[cq + 64] = a2[q] - lse;
                erow[cq + 96] = a3[q] - lse;
            }
        }
        __syncthreads();
        #pragma unroll
        for (int c = 0; c < 8; ++c) {
            const int fi = c * 2048 + tid * 4;
            const int row = fi >> 10, col = fi & 1023;
            f32x4 v = *reinterpret_cast<const f32x4*>(ebuf + row * ESTRIDE + col);
            __builtin_nontemporal_store(v, reinterpret_cast<f32x4*>(
                out + ((size_t)(r * 32 + h2 * 16 + row)) * CC + col));
        }
        __syncthreads();
    }
}

// ---- fallback fused joint (round-2 kernel) for small ws ----
__global__ __launch_bounds__(1024) void joint_fused(
    const float* __restrict__ ep, const float* __restrict__ dp,
    const unsigned short* __restrict__ w2p, float* __restrict__ out)
{
    __shared__ __align__(16) unsigned char ldsA[64 * 1024];
    __shared__ float maxbuf[64][17];
    __shared__ float sumbuf[64][17];
    __shared__ float rowmax_s[64];
    __shared__ float rowlse[64];

    const int bid = blockIdx.x;
    const int bt  = bid >> 1;
    const int u0  = (bid & 1) * 64;
    const int b   = bt >> 8;
    const int tid = threadIdx.x;
    {
        const int row = tid >> 4;
        const int kq  = tid & 15;
        const float* eprow = ep + (size_t)bt * DD;
        const float* dprow = dp + (size_t)(b * UU + u0 + row) * DD;
        #pragma unroll
        for (int c = 0; c < 4; ++c) {
            const int ktag = kq + c * 16;
            const int k0 = ktag * 8;
            float4 e0 = *reinterpret_cast<const float4*>(eprow + k0);
            float4 e1 = *reinterpret_cast<const float4*>(eprow + k0 + 4);
            float4 d0 = *reinterpret_cast<const float4*>(dprow + k0);
            float4 d1 = *reinterpret_cast<const float4*>(dprow + k0 + 4);
            float h0 = tanh_fast(e0.x + d0.x), h1 = tanh_fast(e0.y + d0.y);
            float h2 = tanh_fast(e0.z + d0.z), h3 = tanh_fast(e0.w + d0.w);
            float h4 = tanh_fast(e1.x + d1.x), h5 = tanh_fast(e1.y + d1.y);
            float h6 = tanh_fast(e1.z + d1.z), h7 = tanh_fast(e1.w + d1.w);
            uint4 pk;
            pk.x = (unsigned)f2bf(h0) | ((unsigned)f2bf(h1) << 16);
            pk.y = (unsigned)f2bf(h2) | ((unsigned)f2bf(h3) << 16);
            pk.z = (unsigned)f2bf(h4) | ((unsigned)f2bf(h5) << 16);
            pk.w = (unsigned)f2bf(h6) | ((unsigned)f2bf(h7) << 16);
            *reinterpret_cast<uint4*>(ldsA + ktag * 1024 + ((row ^ (ktag & 7)) << 4)) = pk;
        }
    }
    __syncthreads();

    const int lane = tid & 63;
    const int w    = tid >> 6;
    const int g    = lane >> 5;
    const int l31  = lane & 31;
    const int col0 = w * 64;

    const unsigned short* wb0 = w2p + (size_t)(col0 + l31) * 8;
    const unsigned short* wb1 = w2p + (size_t)(col0 + 32 + l31) * 8;

    f32x16 acc00 = {}, acc01 = {}, acc10 = {}, acc11 = {};
    bf16x8 bf0 = *reinterpret_cast<const bf16x8*>(wb0 + (size_t)g * (CC * 8));
    bf16x8 bf1 = *reinterpret_cast<const bf16x8*>(wb1 + (size_t)g * (CC * 8));

    #pragma unroll 2
    for (int kk = 0; kk < 32; ++kk) {
        const int ktag = kk * 2 + g;
        const unsigned char* ab = ldsA + ktag * 1024 + ((l31 ^ (ktag & 7)) << 4);
        bf16x8 fa0 = *reinterpret_cast<const bf16x8*>(ab);
        bf16x8 fa1 = *reinterpret_cast<const bf16x8*>(ab + 512);
        const int ktn = ((kk + 1) & 31) * 2 + g;
        bf16x8 nb0 = *reinterpret_cast<const bf16x8*>(wb0 + (size_t)ktn * (CC * 8));
        bf16x8 nb1 = *reinterpret_cast<const bf16x8*>(wb1 + (size_t)ktn * (CC * 8));
        acc00 = __builtin_amdgcn_mfma_f32_32x32x16_bf16(fa0, bf0, acc00, 0, 0, 0);
        acc10 = __builtin_amdgcn_mfma_f32_32x32x16_bf16(fa1, bf0, acc10, 0, 0, 0);
        acc01 = __builtin_amdgcn_mfma_f32_32x32x16_bf16(fa0, bf1, acc01, 0, 0, 0);
        acc11 = __builtin_amdgcn_mfma_f32_32x32x16_bf16(fa1, bf1, acc11, 0, 0, 0);
        bf0 = nb0; bf1 = nb1;
    }

    #pragma unroll
    for (int i = 0; i < 2; ++i) {
        float pr[16];
        #pragma unroll
        for (int q = 0; q < 16; ++q)
            pr[q] = (i == 0) ? fmaxf(acc00[q], acc01[q]) : fmaxf(acc10[q], acc11[q]);
        #pragma unroll
        for (int off = 16; off >= 1; off >>= 1)
            #pragma unroll
            for (int q = 0; q < 16; ++q)
                pr[q] = fmaxf(pr[q], __shfl_xor(pr[q], off, 64));
        if (l31 == 0)
            #pragma unroll
            for (int q = 0; q < 16; ++q)
                maxbuf[i * 32 + (q & 3) + 8 * (q >> 2) + 4 * g][w] = pr[q];
    }
    __syncthreads();
    if (tid < 64) {
        float mm = maxbuf[tid][0];
        #pragma unroll
        for (int j = 1; j < 16; ++j) mm = fmaxf(mm, maxbuf[tid][j]);
        rowmax_s[tid] = mm;
    }
    __syncthreads();
    #pragma unroll
    for (int i = 0; i < 2; ++i) {
        float ps[16];
        #pragma unroll
        for (int q = 0; q < 16; ++q) {
            const int r32 = i * 32 + (q & 3) + 8 * (q >> 2) + 4 * g;
            const float rm = rowmax_s[r32];
            ps[q] = (i == 0) ? __expf(acc00[q] - rm) + __expf(acc01[q] - rm)
                             : __expf(acc10[q] - rm) + __expf(acc11[q] - rm);
        }
        #pragma unroll
        for (int off = 16; off >= 1; off >>= 1)
            #pragma unroll
            for (int q = 0; q < 16; ++q)
                ps[q] += __shfl_xor(ps[q], off, 64);
        if (l31 == 0)
            #pragma unroll
            for (int q = 0; q < 16; ++q)
                sumbuf[i * 32 + (q & 3) + 8 * (q >> 2) + 4 * g][w] = ps[q];
    }
    __syncthreads();
    if (tid < 64) {
        float ss = 0.f;
        #pragma unroll
        for (int j = 0; j < 16; ++j) ss += sumbuf[tid][j];
        rowlse[tid] = rowmax_s[tid] + __logf(ss);
    }
    __syncthreads();

    float* outp = out + ((size_t)(bt * UU + u0)) * CC + col0 + l31;
    #pragma unroll
    for (int q = 0; q < 16; ++q) {
        const int r32 = (q & 3) + 8 * (q >> 2) + 4 * g;
        const float l0 = rowlse[r32];
        const float l1 = rowlse[32 + r32];
        outp[(size_t)r32 * CC]              = acc00[q] - l0;
        outp[(size_t)r32 * CC + 32]         = acc01[q] - l0;
        outp[(size_t)(32 + r32) * CC]       = acc10[q] - l1;
        outp[(size_t)(32 + r32) * CC + 32]  = acc11[q] - l1;
    }
}

extern "C" void kernel_launch(void* const* d_in, const int* in_sizes, int n_in,
                              void* d_out, int out_size, void* d_ws, size_t ws_size,
                              hipStream_t stream) {
    const float* enc = (const float*)d_in[0];
    const float* dec = (const float*)d_in[1];
    const float* W_e = (const float*)d_in[2];
    const float* W_d = (const float*)d_in[3];
    const float* b1  = (const float*)d_in[4];
    const float* W2  = (const float*)d_in[5];
    float* out = (float*)d_out;

    char* ws = (char*)d_ws;
    float* ep = (float*)(ws);                                  // 2MB
    float* dp = (float*)(ws + (2u << 20));                     // 1MB
    unsigned short* w2p = (unsigned short*)(ws + (3u << 20));  // 1MB
    u32x4* hidp = (u32x4*)(ws + (4u << 20));                   // 128MB

    hipLaunchKernelGGL(pack_w2, dim3((DD * CC) / 256), dim3(256), 0, stream, W2, w2p);
    hipLaunchKernelGGL(proj_fused, dim3((BB * TT + BB * UU) / 32, DD / 64), dim3(256), 0,
                       stream, enc, dec, W_e, W_d, b1, ep, dp);

    const size_t need = (size_t)(4u << 20) + (size_t)128 * 1024 * 1024;
    if (ws_size >= need) {
        hipLaunchKernelGGL(hidden_gen, dim3((BB * TT * UU * 64) / 256), dim3(256), 0,
                           stream, ep, dp, hidp);
        hipLaunchKernelGGL(gemm_lsm, dim3(BB * TT * UU / 32), dim3(512), 0, stream,
                           hidp, w2p, out);
    } else {
        hipLaunchKernelGGL(joint_fused, dim3(BB * TT * 2), dim3(1024), 0, stream,
                           ep, dp, w2p, out);
    }
}